// Round 1
// baseline (356.953 us; speedup 1.0000x reference)
//
#include <hip/hip_runtime.h>
#include <hip/hip_bf16.h>
#include <stdint.h>

typedef __bf16 bf16x8 __attribute__((ext_vector_type(8)));
typedef float  f32x4  __attribute__((ext_vector_type(4)));
typedef unsigned short u16;
typedef u16 u16x8 __attribute__((ext_vector_type(8)));

__device__ __forceinline__ u16 f2b(float f) {
  uint32_t u = __builtin_bit_cast(uint32_t, f);
  u += 0x7fffu + ((u >> 16) & 1u);
  return (u16)(u >> 16);
}

__device__ __forceinline__ f32x4 mfma16(bf16x8 a, bf16x8 b, f32x4 c) {
  return __builtin_amdgcn_mfma_f32_16x16x32_bf16(a, b, c, 0, 0, 0);
}

__device__ __forceinline__ void gload_lds16(const void* g, void* l) {
  __builtin_amdgcn_global_load_lds(
      (const __attribute__((address_space(1))) void*)g,
      (__attribute__((address_space(3))) void*)l, 16, 0, 0);
}

// ---------------- fp32 -> bf16 bulk convert (8 elems/thread) ----------------
__global__ void f2b_conv(const float* __restrict__ in, u16* __restrict__ out, int n8) {
  const int i = blockIdx.x * blockDim.x + threadIdx.x;
  if (i >= n8) return;
  const float4* p = (const float4*)in + (size_t)i * 2;
  float4 a = p[0], b = p[1];
  u16x8 r;
  r[0] = f2b(a.x); r[1] = f2b(a.y); r[2] = f2b(a.z); r[3] = f2b(a.w);
  r[4] = f2b(b.x); r[5] = f2b(b.y); r[6] = f2b(b.z); r[7] = f2b(b.w);
  *((u16x8*)out + i) = r;
}

// ---------------- GEMM: C[M][N] = A[M][K] * W[N][K]^T  (+epilogue) ----------
// MODE 0: QKV scatter (o0=q [bh][n][64], o1=k [bh][n][64], o2=vt [bh][64][n])
// MODE 1: fp32 out + bias
// MODE 2: bf16 out + bias + exact gelu
template<int MODE>
__global__ __launch_bounds__(256, 2) void gemm_bt(
    const u16* __restrict__ A, const u16* __restrict__ W,
    const float* __restrict__ bias,
    void* __restrict__ o0, void* __restrict__ o1, void* __restrict__ o2,
    int Nsz, int Ksz)
{
  __shared__ u16 As[128 * 32];
  __shared__ u16 Bs[128 * 32];
  const int nbn = Nsz >> 7;
  const int bm = blockIdx.x / nbn;
  const int bn = blockIdx.x % nbn;
  const int tid = threadIdx.x;
  const int w = tid >> 6, l = tid & 63;
  const int lh = l >> 4, ll = l & 15;
  const int wr = w >> 1, wc = w & 1;

  f32x4 acc[4][4] = {};

  const u16* Ag = A + (size_t)(bm * 128) * Ksz;
  const u16* Wg = W + (size_t)(bn * 128) * Ksz;

  for (int k0 = 0; k0 < Ksz; k0 += 32) {
    __syncthreads();
#pragma unroll
    for (int j = 0; j < 2; ++j) {
      const int flat = (w * 2 + j) * 64 + l;
      const int row = flat >> 2, sl = flat & 3;
      gload_lds16(Ag + (size_t)row * Ksz + k0 + sl * 8, As + (w * 2 + j) * 512);
      gload_lds16(Wg + (size_t)row * Ksz + k0 + sl * 8, Bs + (w * 2 + j) * 512);
    }
    __syncthreads();
    bf16x8 af[4], bfr[4];
#pragma unroll
    for (int mi = 0; mi < 4; ++mi)
      af[mi] = *(const bf16x8*)(As + (wr * 64 + mi * 16 + ll) * 32 + lh * 8);
#pragma unroll
    for (int ni = 0; ni < 4; ++ni)
      bfr[ni] = *(const bf16x8*)(Bs + (wc * 64 + ni * 16 + ll) * 32 + lh * 8);
#pragma unroll
    for (int mi = 0; mi < 4; ++mi)
#pragma unroll
      for (int ni = 0; ni < 4; ++ni)
        acc[mi][ni] = mfma16(af[mi], bfr[ni], acc[mi][ni]);
  }

#pragma unroll
  for (int mi = 0; mi < 4; ++mi) {
#pragma unroll
    for (int ni = 0; ni < 4; ++ni) {
      const int col = bn * 128 + wc * 64 + ni * 16 + ll;
#pragma unroll
      for (int i = 0; i < 4; ++i) {
        const int row = bm * 128 + wr * 64 + mi * 16 + lh * 4 + i;
        float v = acc[mi][ni][i];
        if (MODE == 1) {
          ((float*)o0)[(size_t)row * Nsz + col] = v + bias[col];
        } else if (MODE == 2) {
          float xx = v + bias[col];
          float gl = 0.5f * xx * (1.0f + erff(xx * 0.70710678118654752f));
          ((u16*)o0)[(size_t)row * Nsz + col] = f2b(gl);
        } else {
          const int which = col >> 10;
          const int e = col & 1023;
          const int hh = e >> 6, dd = e & 63;
          const int bb = row >> 11, nl = row & 2047;
          const u16 bv = f2b(v);
          if (which == 0)
            ((u16*)o0)[((size_t)(bb * 16 + hh) * 2048 + nl) * 64 + dd] = bv;
          else if (which == 1)
            ((u16*)o1)[((size_t)(bb * 16 + hh) * 2048 + nl) * 64 + dd] = bv;
          else
            ((u16*)o2)[((size_t)(bb * 16 + hh) * 64 + dd) * 2048 + nl] = bv;
        }
      }
    }
  }
}

// ---------------- flash attention (non-causal), 64 q-rows/block -------------
// Q,K: bf16 [32][2048][64]; Vt: bf16 [32][64][2048]; ctx: bf16 [4096][1024]
__global__ __launch_bounds__(256, 2) void attn_fwd(
    const u16* __restrict__ Q, const u16* __restrict__ K,
    const u16* __restrict__ Vt, u16* __restrict__ ctx)
{
  __shared__ u16 Ks[64 * 64];
  __shared__ u16 Vs[64 * 64];
  __shared__ u16 Ps[4][16 * 64];

  const int bh = blockIdx.x & 31;
  const int qt = blockIdx.x >> 5;
  const int tid = threadIdx.x;
  const int w = tid >> 6, l = tid & 63;
  const int lh = l >> 4, ll = l & 15;
  const int q0 = qt * 64 + w * 16;

  bf16x8 qf[2];
  {
    const u16* Qg = Q + ((size_t)bh * 2048 + q0 + ll) * 64;
#pragma unroll
    for (int kk = 0; kk < 2; ++kk)
      qf[kk] = *(const bf16x8*)(Qg + kk * 32 + lh * 8);
  }

  f32x4 cacc[4] = {};
  float mrow[4] = {-1e30f, -1e30f, -1e30f, -1e30f};
  float lrow[4] = {0.f, 0.f, 0.f, 0.f};
  u16* ps = Ps[w];
  const float scale = 0.125f;  // 1/sqrt(64)

  for (int kt = 0; kt < 32; ++kt) {
    __syncthreads();
#pragma unroll
    for (int j = 0; j < 2; ++j) {
      const int flat = (w * 2 + j) * 64 + l;
      const int row = flat >> 3, sl = flat & 7;
      const int gsl = sl ^ (row & 7);  // pre-swizzled global source (linear LDS dest)
      gload_lds16(K + ((size_t)bh * 2048 + (size_t)kt * 64 + row) * 64 + gsl * 8,
                  Ks + (w * 2 + j) * 512);
      gload_lds16(Vt + ((size_t)bh * 64 + row) * 2048 + (size_t)kt * 64 + gsl * 8,
                  Vs + (w * 2 + j) * 512);
    }
    __syncthreads();

    // S = Q K^T  (16 q-rows x 64 keys per wave)
    f32x4 s[4];
#pragma unroll
    for (int jb = 0; jb < 4; ++jb) {
      f32x4 a = {};
#pragma unroll
      for (int kk = 0; kk < 2; ++kk) {
        const int r = jb * 16 + ll;
        const int sg = kk * 4 + lh;
        bf16x8 kf = *(const bf16x8*)(Ks + r * 64 + ((sg ^ (r & 7)) * 8));
        a = mfma16(qf[kk], kf, a);
      }
      s[jb] = a;
    }

    // online softmax (wave-parallel: shfl over the 16-lane column group)
    float al[4];
#pragma unroll
    for (int i = 0; i < 4; ++i) {
      float mx = fmaxf(fmaxf(s[0][i], s[1][i]), fmaxf(s[2][i], s[3][i])) * scale;
#pragma unroll
      for (int d = 1; d < 16; d <<= 1) mx = fmaxf(mx, __shfl_xor(mx, d));
      const float mn = fmaxf(mrow[i], mx);
      al[i] = __expf(mrow[i] - mn);
      mrow[i] = mn;
    }

    float ts[4] = {0.f, 0.f, 0.f, 0.f};
    u16 pb[4][4];
#pragma unroll
    for (int jb = 0; jb < 4; ++jb)
#pragma unroll
      for (int i = 0; i < 4; ++i) {
        const float p = __expf(s[jb][i] * scale - mrow[i]);
        ts[i] += p;
        pb[jb][i] = f2b(p);
      }
#pragma unroll
    for (int i = 0; i < 4; ++i) {
      float t = ts[i];
#pragma unroll
      for (int d = 1; d < 16; d <<= 1) t += __shfl_xor(t, d);
      lrow[i] = lrow[i] * al[i] + t;
#pragma unroll
      for (int db = 0; db < 4; ++db) cacc[db][i] *= al[i];
    }

    // P: C-layout -> A-layout via wave-private LDS (swizzled rows)
#pragma unroll
    for (int jb = 0; jb < 4; ++jb)
#pragma unroll
      for (int i = 0; i < 4; ++i) {
        const int pr = lh * 4 + i;
        const int pc = jb * 16 + ll;
        const int slp = (pc >> 3) ^ (pr & 7);
        ps[pr * 64 + slp * 8 + (pc & 7)] = pb[jb][i];
      }
    asm volatile("s_waitcnt lgkmcnt(0)" ::: "memory");

    // ctx += P * V
#pragma unroll
    for (int kk = 0; kk < 2; ++kk) {
      const int psl = (kk * 4 + lh) ^ (ll & 7);
      bf16x8 pf = *(const bf16x8*)(ps + ll * 64 + psl * 8);
#pragma unroll
      for (int db = 0; db < 4; ++db) {
        const int vr = db * 16 + ll;
        const int vsl = (kk * 4 + lh) ^ (vr & 7);
        bf16x8 vf = *(const bf16x8*)(Vs + vr * 64 + vsl * 8);
        cacc[db] = mfma16(pf, vf, cacc[db]);
      }
    }
  }

  const int bb = bh >> 4, hh = bh & 15;
#pragma unroll
  for (int db = 0; db < 4; ++db)
#pragma unroll
    for (int i = 0; i < 4; ++i) {
      const float v = cacc[db][i] / lrow[i];
      const size_t orow = (size_t)bb * 2048 + q0 + lh * 4 + i;
      const size_t ocol = (size_t)hh * 64 + db * 16 + ll;
      ctx[orow * 1024 + ocol] = f2b(v);
    }
}

// ---------------- fused residual + LayerNorm (row = 1024 fp32) --------------
__global__ __launch_bounds__(256) void ln_fused(
    const float* __restrict__ a, const float* __restrict__ b,
    const float* __restrict__ g, const float* __restrict__ be,
    float* __restrict__ ho, u16* __restrict__ hb)
{
  const int row = blockIdx.x;
  const int t = threadIdx.x;
  const size_t base = (size_t)row * 1024 + t * 4;
  float4 xa = *(const float4*)(a + base);
  float4 xb = *(const float4*)(b + base);
  float v0 = xa.x + xb.x, v1 = xa.y + xb.y, v2 = xa.z + xb.z, v3 = xa.w + xb.w;
  float s = v0 + v1 + v2 + v3;
  float ss = v0 * v0 + v1 * v1 + v2 * v2 + v3 * v3;
#pragma unroll
  for (int d = 1; d < 64; d <<= 1) {
    s += __shfl_xor(s, d);
    ss += __shfl_xor(ss, d);
  }
  __shared__ float red[8];
  const int w = t >> 6, l = t & 63;
  if (l == 0) { red[w] = s; red[4 + w] = ss; }
  __syncthreads();
  s = red[0] + red[1] + red[2] + red[3];
  ss = red[4] + red[5] + red[6] + red[7];
  const float mean = s * (1.0f / 1024.0f);
  const float var = ss * (1.0f / 1024.0f) - mean * mean;
  const float rstd = rsqrtf(var + 1e-5f);
  const float vv[4] = {v0, v1, v2, v3};
#pragma unroll
  for (int i = 0; i < 4; ++i) {
    const int col = t * 4 + i;
    const float hv = (vv[i] - mean) * rstd * g[col] + be[col];
    if (ho) ho[base + i] = hv;
    if (hb) hb[base + i] = f2b(hv);
  }
}

// ---------------------------------------------------------------------------
extern "C" void kernel_launch(void* const* d_in, const int* in_sizes, int n_in,
                              void* d_out, int out_size, void* d_ws, size_t ws_size,
                              hipStream_t stream) {
  const float* x   = (const float*)d_in[0];
  const float* wq  = (const float*)d_in[1];
  const float* wk  = (const float*)d_in[2];
  const float* wv  = (const float*)d_in[3];
  const float* wo  = (const float*)d_in[4];
  const float* bo  = (const float*)d_in[5];
  const float* g1  = (const float*)d_in[6];
  const float* b1  = (const float*)d_in[7];
  const float* w1  = (const float*)d_in[8];
  const float* bf1 = (const float*)d_in[9];
  const float* w2  = (const float*)d_in[10];
  const float* bf2 = (const float*)d_in[11];
  const float* g2  = (const float*)d_in[12];
  const float* b2  = (const float*)d_in[13];

  char* ws = (char*)d_ws;
  const size_t MB = 1u << 20;
  u16* xb    = (u16*)(ws + 0);        //  8 MB  x bf16 [4096][1024]
  u16* wqkv  = (u16*)(ws + 8 * MB);   //  6 MB  wq|wk|wv bf16 [3072][1024]
  u16* wob   = (u16*)(ws + 14 * MB);  //  2 MB
  u16* w1b   = (u16*)(ws + 16 * MB);  //  8 MB
  u16* w2b   = (u16*)(ws + 24 * MB);  //  8 MB
  u16* qb    = (u16*)(ws + 32 * MB);  //  8 MB  [32][2048][64]
  u16* kb    = (u16*)(ws + 40 * MB);  //  8 MB
  u16* vtb   = (u16*)(ws + 48 * MB);  //  8 MB  [32][64][2048]
  u16* ctxb  = (u16*)(ws + 56 * MB);  //  8 MB  [4096][1024]
  float* tmp  = (float*)(ws + 64 * MB);  // 16 MB (attn_out, then ff2)
  float* hbuf = (float*)(ws + 80 * MB);  // 16 MB
  u16* hbb   = (u16*)(ws + 96 * MB);  //  8 MB
  u16* ff1   = (u16*)(ws + 32 * MB);  // 32 MB, reuses q/k/vt/ctx (dead by then)

  // fp32 -> bf16
  f2b_conv<<<2048, 256, 0, stream>>>(x, xb, 524288);
  f2b_conv<<<512, 256, 0, stream>>>(wq, wqkv, 131072);
  f2b_conv<<<512, 256, 0, stream>>>(wk, wqkv + 1048576, 131072);
  f2b_conv<<<512, 256, 0, stream>>>(wv, wqkv + 2097152, 131072);
  f2b_conv<<<512, 256, 0, stream>>>(wo, wob, 131072);
  f2b_conv<<<2048, 256, 0, stream>>>(w1, w1b, 524288);
  f2b_conv<<<2048, 256, 0, stream>>>(w2, w2b, 524288);

  // fused QKV projection
  gemm_bt<0><<<32 * 24, 256, 0, stream>>>(xb, wqkv, nullptr, qb, kb, vtb, 3072, 1024);
  // attention
  attn_fwd<<<1024, 256, 0, stream>>>(qb, kb, vtb, ctxb);
  // output projection (+bo)
  gemm_bt<1><<<32 * 8, 256, 0, stream>>>(ctxb, wob, bo, tmp, nullptr, nullptr, 1024, 1024);
  // h = LN(x + attn_out)
  ln_fused<<<4096, 256, 0, stream>>>(x, tmp, g1, b1, hbuf, hbb);
  // ff1 = gelu(h @ w1^T + bf1)
  gemm_bt<2><<<32 * 32, 256, 0, stream>>>(hbb, w1b, bf1, ff1, nullptr, nullptr, 4096, 1024);
  // ff2 = ff1 @ w2^T + bf2
  gemm_bt<1><<<32 * 8, 256, 0, stream>>>(ff1, w2b, bf2, tmp, nullptr, nullptr, 1024, 4096);
  // out = LN(h + ff2)
  ln_fused<<<4096, 256, 0, stream>>>(hbuf, tmp, g2, b2, (float*)d_out, nullptr);
}

// Round 2
// 324.168 us; speedup vs baseline: 1.1011x; 1.1011x over previous
//
#include <hip/hip_runtime.h>
#include <hip/hip_bf16.h>
#include <stdint.h>

typedef __bf16 bf16x8 __attribute__((ext_vector_type(8)));
typedef float  f32x4  __attribute__((ext_vector_type(4)));
typedef unsigned short u16;
typedef u16 u16x8 __attribute__((ext_vector_type(8)));

__device__ __forceinline__ u16 f2b(float f) {
  uint32_t u = __builtin_bit_cast(uint32_t, f);
  u += 0x7fffu + ((u >> 16) & 1u);
  return (u16)(u >> 16);
}

__device__ __forceinline__ f32x4 mfma16(bf16x8 a, bf16x8 b, f32x4 c) {
  return __builtin_amdgcn_mfma_f32_16x16x32_bf16(a, b, c, 0, 0, 0);
}

__device__ __forceinline__ void gload_lds16(const void* g, void* l) {
  __builtin_amdgcn_global_load_lds(
      (const __attribute__((address_space(1))) void*)g,
      (__attribute__((address_space(3))) void*)l, 16, 0, 0);
}

// ---------------- fp32 -> bf16 bulk convert (8 elems/thread) ----------------
__global__ void f2b_conv(const float* __restrict__ in, u16* __restrict__ out, int n8) {
  const int i = blockIdx.x * blockDim.x + threadIdx.x;
  if (i >= n8) return;
  const float4* p = (const float4*)in + (size_t)i * 2;
  float4 a = p[0], b = p[1];
  u16x8 r;
  r[0] = f2b(a.x); r[1] = f2b(a.y); r[2] = f2b(a.z); r[3] = f2b(a.w);
  r[4] = f2b(b.x); r[5] = f2b(b.y); r[6] = f2b(b.z); r[7] = f2b(b.w);
  *((u16x8*)out + i) = r;
}

// ---------------- GEMM: C[M][N] = A[M][K] * W[N][K]^T  (+epilogue) ----------
// MODE 0: QKV scatter (o0=q*0.125 [bh][n][64], o1=k [bh][n][64], o2=vt [bh][64][n])
// MODE 1: fp32 out + bias
// MODE 2: bf16 out + bias + exact gelu
template<int MODE>
__global__ __launch_bounds__(256, 3) void gemm_bt(
    const u16* __restrict__ A, const u16* __restrict__ W,
    const float* __restrict__ bias,
    void* __restrict__ o0, void* __restrict__ o1, void* __restrict__ o2,
    int Nsz, int Ksz)
{
  __shared__ u16 As[2][128 * 32];
  __shared__ u16 Bs[2][128 * 32];
  const int nbn = Nsz >> 7;
  int bid = blockIdx.x;
  bid = (bid & 7) * ((int)gridDim.x >> 3) + (bid >> 3);  // XCD-aware swizzle (grid%8==0)
  const int bm = bid / nbn;
  const int bn = bid % nbn;
  const int tid = threadIdx.x;
  const int w = tid >> 6, l = tid & 63;
  const int lh = l >> 4, ll = l & 15;
  const int wr = w >> 1, wc = w & 1;

  f32x4 acc[4][4] = {};

  const u16* Ag = A + (size_t)(bm * 128) * Ksz;
  const u16* Wg = W + (size_t)(bn * 128) * Ksz;

  const int flat0 = (w * 2) * 64 + l;
  const int flat1 = (w * 2 + 1) * 64 + l;

  // prologue: stage k-step 0 into buf 0
  {
    gload_lds16(Ag + (size_t)(flat0 >> 2) * Ksz + (flat0 & 3) * 8, As[0] + flat0 * 8);
    gload_lds16(Wg + (size_t)(flat0 >> 2) * Ksz + (flat0 & 3) * 8, Bs[0] + flat0 * 8);
    gload_lds16(Ag + (size_t)(flat1 >> 2) * Ksz + (flat1 & 3) * 8, As[0] + flat1 * 8);
    gload_lds16(Wg + (size_t)(flat1 >> 2) * Ksz + (flat1 & 3) * 8, Bs[0] + flat1 * 8);
  }
  __syncthreads();

  const int NS = Ksz >> 5;
  int buf = 0;
  for (int s = 0; s < NS; ++s) {
    // issue next-tile stage FIRST (2-phase: loads in flight under compute)
    if (s + 1 < NS) {
      const int k0 = (s + 1) * 32;
      gload_lds16(Ag + (size_t)(flat0 >> 2) * Ksz + k0 + (flat0 & 3) * 8, As[buf ^ 1] + flat0 * 8);
      gload_lds16(Wg + (size_t)(flat0 >> 2) * Ksz + k0 + (flat0 & 3) * 8, Bs[buf ^ 1] + flat0 * 8);
      gload_lds16(Ag + (size_t)(flat1 >> 2) * Ksz + k0 + (flat1 & 3) * 8, As[buf ^ 1] + flat1 * 8);
      gload_lds16(Wg + (size_t)(flat1 >> 2) * Ksz + k0 + (flat1 & 3) * 8, Bs[buf ^ 1] + flat1 * 8);
    }
    bf16x8 af[4], bfr[4];
#pragma unroll
    for (int mi = 0; mi < 4; ++mi)
      af[mi] = *(const bf16x8*)(As[buf] + (wr * 64 + mi * 16 + ll) * 32 + lh * 8);
#pragma unroll
    for (int ni = 0; ni < 4; ++ni)
      bfr[ni] = *(const bf16x8*)(Bs[buf] + (wc * 64 + ni * 16 + ll) * 32 + lh * 8);
    __builtin_amdgcn_s_setprio(1);
#pragma unroll
    for (int mi = 0; mi < 4; ++mi)
#pragma unroll
      for (int ni = 0; ni < 4; ++ni)
        acc[mi][ni] = mfma16(af[mi], bfr[ni], acc[mi][ni]);
    __builtin_amdgcn_s_setprio(0);
    __syncthreads();  // drains vmcnt for staged buf^1 + protects dbuf reuse
    buf ^= 1;
  }

#pragma unroll
  for (int mi = 0; mi < 4; ++mi) {
#pragma unroll
    for (int ni = 0; ni < 4; ++ni) {
      const int col = bn * 128 + wc * 64 + ni * 16 + ll;
#pragma unroll
      for (int i = 0; i < 4; ++i) {
        const int row = bm * 128 + wr * 64 + mi * 16 + lh * 4 + i;
        float v = acc[mi][ni][i];
        if (MODE == 1) {
          ((float*)o0)[(size_t)row * Nsz + col] = v + bias[col];
        } else if (MODE == 2) {
          float xx = v + bias[col];
          float gl = 0.5f * xx * (1.0f + erff(xx * 0.70710678118654752f));
          ((u16*)o0)[(size_t)row * Nsz + col] = f2b(gl);
        } else {
          const int which = col >> 10;
          const int e = col & 1023;
          const int hh = e >> 6, dd = e & 63;
          const int bb = row >> 11, nl = row & 2047;
          if (which == 0) {  // q, pre-scaled by 1/sqrt(D)
            ((u16*)o0)[((size_t)(bb * 16 + hh) * 2048 + nl) * 64 + dd] = f2b(v * 0.125f);
          } else if (which == 1) {
            ((u16*)o1)[((size_t)(bb * 16 + hh) * 2048 + nl) * 64 + dd] = f2b(v);
          } else {
            ((u16*)o2)[((size_t)(bb * 16 + hh) * 64 + dd) * 2048 + nl] = f2b(v);
          }
        }
      }
    }
  }
}

// ---------------- flash attention (non-causal), swapped QK^T ----------------
// Q,K: bf16 [32][2048][64] (Q pre-scaled); Vt: bf16 [32][64][2048]; ctx: bf16 [4096][1024]
__global__ __launch_bounds__(256, 4) void attn_fwd(
    const u16* __restrict__ Q, const u16* __restrict__ K,
    const u16* __restrict__ Vt, u16* __restrict__ ctx)
{
  __shared__ u16 Ks[2][64 * 64];
  __shared__ u16 Vs[2][64 * 64];
  __shared__ u16 Ps[4][16 * 64];

  const int bh = blockIdx.x & 31;
  const int qt = blockIdx.x >> 5;
  const int tid = threadIdx.x;
  const int w = tid >> 6, l = tid & 63;
  const int lh = l >> 4, ll = l & 15;
  const int q0 = qt * 64 + w * 16;

  bf16x8 qf[2];
  {
    const u16* Qg = Q + ((size_t)bh * 2048 + q0 + ll) * 64;
#pragma unroll
    for (int kk = 0; kk < 2; ++kk)
      qf[kk] = *(const bf16x8*)(Qg + kk * 32 + lh * 8);
  }

  f32x4 cacc[4] = {};
  float m_l = -1e30f;  // running max for query ll (uniform over lh)
  float l_l = 0.f;     // running sum for query ll
  u16* ps = Ps[w];

  const int f0 = tid, f1 = 256 + tid;
  const int r0 = f0 >> 3, s0 = f0 & 7, g0 = (s0 ^ (r0 & 7)) * 8;
  const int r1 = f1 >> 3, s1 = f1 & 7, g1 = (s1 ^ (r1 & 7)) * 8;

  // prologue: stage kt=0 into buf 0 (swizzled source, linear LDS dest)
  {
    gload_lds16(K + ((size_t)bh * 2048 + r0) * 64 + g0, Ks[0] + f0 * 8);
    gload_lds16(Vt + ((size_t)bh * 64 + r0) * 2048 + g0, Vs[0] + f0 * 8);
    gload_lds16(K + ((size_t)bh * 2048 + r1) * 64 + g1, Ks[0] + f1 * 8);
    gload_lds16(Vt + ((size_t)bh * 64 + r1) * 2048 + g1, Vs[0] + f1 * 8);
  }
  __syncthreads();

  for (int kt = 0; kt < 32; ++kt) {
    const int b = kt & 1;
    if (kt < 31) {  // stage kt+1 early; drains only at end-of-tile barrier
      const int kn = (kt + 1) * 64;
      gload_lds16(K + ((size_t)bh * 2048 + kn + r0) * 64 + g0, Ks[b ^ 1] + f0 * 8);
      gload_lds16(Vt + ((size_t)bh * 64 + r0) * 2048 + kn + g0, Vs[b ^ 1] + f0 * 8);
      gload_lds16(K + ((size_t)bh * 2048 + kn + r1) * 64 + g1, Ks[b ^ 1] + f1 * 8);
      gload_lds16(Vt + ((size_t)bh * 64 + r1) * 2048 + kn + g1, Vs[b ^ 1] + f1 * 8);
    }

    // S^T = K Q^T : lane holds S[key=jb*16+lh*4+i][q=ll]
    f32x4 st[4];
    __builtin_amdgcn_s_setprio(1);
#pragma unroll
    for (int jb = 0; jb < 4; ++jb) {
      f32x4 a = {};
#pragma unroll
      for (int kk = 0; kk < 2; ++kk) {
        const int r = jb * 16 + ll;
        bf16x8 kf = *(const bf16x8*)(Ks[b] + r * 64 + (((kk * 4 + lh) ^ (r & 7)) * 8));
        a = mfma16(kf, qf[kk], a);  // swapped: A=K, B=Q
      }
      st[jb] = a;
    }
    __builtin_amdgcn_s_setprio(0);

    // per-lane softmax over 16 regs + 2-step cross-lh reduce
    float mx = fmaxf(fmaxf(fmaxf(st[0][0], st[0][1]), fmaxf(st[0][2], st[0][3])),
                     fmaxf(fmaxf(st[1][0], st[1][1]), fmaxf(st[1][2], st[1][3])));
    mx = fmaxf(mx, fmaxf(fmaxf(fmaxf(st[2][0], st[2][1]), fmaxf(st[2][2], st[2][3])),
                         fmaxf(fmaxf(st[3][0], st[3][1]), fmaxf(st[3][2], st[3][3]))));
    mx = fmaxf(mx, __shfl_xor(mx, 16));
    mx = fmaxf(mx, __shfl_xor(mx, 32));
    const float mn = fmaxf(m_l, mx);
    const float al = __expf(m_l - mn);
    m_l = mn;

    float sum = 0.f;
#pragma unroll
    for (int jb = 0; jb < 4; ++jb) {
      const float p0 = __expf(st[jb][0] - m_l);
      const float p1 = __expf(st[jb][1] - m_l);
      const float p2 = __expf(st[jb][2] - m_l);
      const float p3 = __expf(st[jb][3] - m_l);
      sum += (p0 + p1) + (p2 + p3);
      uint2 pk;
      pk.x = (uint32_t)f2b(p0) | ((uint32_t)f2b(p1) << 16);
      pk.y = (uint32_t)f2b(p2) | ((uint32_t)f2b(p3) << 16);
      // P[q=ll][key=jb*16+lh*4+i], row 64 keys, 16B-slot XOR-swizzled by q
      *(uint2*)(ps + ll * 64 + (((jb * 2 + (lh >> 1)) ^ (ll & 7)) * 8) + (lh & 1) * 4) = pk;
    }
    sum += __shfl_xor(sum, 16);
    sum += __shfl_xor(sum, 32);
    l_l = l_l * al + sum;

    // broadcast al to C-layout rows (query lh*4+i) and rescale O
    float alq[4];
#pragma unroll
    for (int i = 0; i < 4; ++i) alq[i] = __shfl(al, lh * 4 + i);
#pragma unroll
    for (int db = 0; db < 4; ++db)
#pragma unroll
      for (int i = 0; i < 4; ++i) cacc[db][i] *= alq[i];

    asm volatile("s_waitcnt lgkmcnt(0)" ::: "memory");
    __builtin_amdgcn_sched_barrier(0);

    // ctx += P * V
    __builtin_amdgcn_s_setprio(1);
#pragma unroll
    for (int kk = 0; kk < 2; ++kk) {
      bf16x8 pf = *(const bf16x8*)(ps + ll * 64 + (((kk * 4 + lh) ^ (ll & 7)) * 8));
#pragma unroll
      for (int db = 0; db < 4; ++db) {
        const int vr = db * 16 + ll;
        bf16x8 vf = *(const bf16x8*)(Vs[b] + vr * 64 + (((kk * 4 + lh) ^ (vr & 7)) * 8));
        cacc[db] = mfma16(pf, vf, cacc[db]);
      }
    }
    __builtin_amdgcn_s_setprio(0);
    __syncthreads();  // drains staged loads for kt+1, protects dbuf
  }

  float lq[4];
#pragma unroll
  for (int i = 0; i < 4; ++i) lq[i] = __shfl(l_l, lh * 4 + i);

  const int bb = bh >> 4, hh = bh & 15;
#pragma unroll
  for (int db = 0; db < 4; ++db)
#pragma unroll
    for (int i = 0; i < 4; ++i) {
      const float v = cacc[db][i] / lq[i];
      const size_t orow = (size_t)bb * 2048 + q0 + lh * 4 + i;
      const size_t ocol = (size_t)hh * 64 + db * 16 + ll;
      ctx[orow * 1024 + ocol] = f2b(v);
    }
}

// ---------------- fused residual + LayerNorm (row = 1024 fp32) --------------
__global__ __launch_bounds__(256) void ln_fused(
    const float* __restrict__ a, const float* __restrict__ b,
    const float* __restrict__ g, const float* __restrict__ be,
    float* __restrict__ ho, u16* __restrict__ hb)
{
  const int row = blockIdx.x;
  const int t = threadIdx.x;
  const size_t base = (size_t)row * 1024 + t * 4;
  float4 xa = *(const float4*)(a + base);
  float4 xb = *(const float4*)(b + base);
  float v0 = xa.x + xb.x, v1 = xa.y + xb.y, v2 = xa.z + xb.z, v3 = xa.w + xb.w;
  float s = v0 + v1 + v2 + v3;
  float ss = v0 * v0 + v1 * v1 + v2 * v2 + v3 * v3;
#pragma unroll
  for (int d = 1; d < 64; d <<= 1) {
    s += __shfl_xor(s, d);
    ss += __shfl_xor(ss, d);
  }
  __shared__ float red[8];
  const int w = t >> 6, l = t & 63;
  if (l == 0) { red[w] = s; red[4 + w] = ss; }
  __syncthreads();
  s = red[0] + red[1] + red[2] + red[3];
  ss = red[4] + red[5] + red[6] + red[7];
  const float mean = s * (1.0f / 1024.0f);
  const float var = ss * (1.0f / 1024.0f) - mean * mean;
  const float rstd = rsqrtf(var + 1e-5f);
  const float vv[4] = {v0, v1, v2, v3};
#pragma unroll
  for (int i = 0; i < 4; ++i) {
    const int col = t * 4 + i;
    const float hv = (vv[i] - mean) * rstd * g[col] + be[col];
    if (ho) ho[base + i] = hv;
    if (hb) hb[base + i] = f2b(hv);
  }
}

// ---------------------------------------------------------------------------
extern "C" void kernel_launch(void* const* d_in, const int* in_sizes, int n_in,
                              void* d_out, int out_size, void* d_ws, size_t ws_size,
                              hipStream_t stream) {
  const float* x   = (const float*)d_in[0];
  const float* wq  = (const float*)d_in[1];
  const float* wk  = (const float*)d_in[2];
  const float* wv  = (const float*)d_in[3];
  const float* wo  = (const float*)d_in[4];
  const float* bo  = (const float*)d_in[5];
  const float* g1  = (const float*)d_in[6];
  const float* b1  = (const float*)d_in[7];
  const float* w1  = (const float*)d_in[8];
  const float* bf1 = (const float*)d_in[9];
  const float* w2  = (const float*)d_in[10];
  const float* bf2 = (const float*)d_in[11];
  const float* g2  = (const float*)d_in[12];
  const float* b2  = (const float*)d_in[13];

  char* ws = (char*)d_ws;
  const size_t MB = 1u << 20;
  u16* xb    = (u16*)(ws + 0);        //  8 MB  x bf16 [4096][1024]
  u16* wqkv  = (u16*)(ws + 8 * MB);   //  6 MB  wq|wk|wv bf16 [3072][1024]
  u16* wob   = (u16*)(ws + 14 * MB);  //  2 MB
  u16* w1b   = (u16*)(ws + 16 * MB);  //  8 MB
  u16* w2b   = (u16*)(ws + 24 * MB);  //  8 MB
  u16* qb    = (u16*)(ws + 32 * MB);  //  8 MB  [32][2048][64]
  u16* kb    = (u16*)(ws + 40 * MB);  //  8 MB
  u16* vtb   = (u16*)(ws + 48 * MB);  //  8 MB  [32][64][2048]
  u16* ctxb  = (u16*)(ws + 56 * MB);  //  8 MB  [4096][1024]
  float* tmp  = (float*)(ws + 64 * MB);  // 16 MB (attn_out, then ff2)
  float* hbuf = (float*)(ws + 80 * MB);  // 16 MB
  u16* hbb   = (u16*)(ws + 96 * MB);  //  8 MB
  u16* ff1   = (u16*)(ws + 32 * MB);  // 32 MB, reuses q/k/vt/ctx (dead by then)

  // fp32 -> bf16
  f2b_conv<<<2048, 256, 0, stream>>>(x, xb, 524288);
  f2b_conv<<<512, 256, 0, stream>>>(wq, wqkv, 131072);
  f2b_conv<<<512, 256, 0, stream>>>(wk, wqkv + 1048576, 131072);
  f2b_conv<<<512, 256, 0, stream>>>(wv, wqkv + 2097152, 131072);
  f2b_conv<<<512, 256, 0, stream>>>(wo, wob, 131072);
  f2b_conv<<<2048, 256, 0, stream>>>(w1, w1b, 524288);
  f2b_conv<<<2048, 256, 0, stream>>>(w2, w2b, 524288);

  // fused QKV projection (q pre-scaled by 1/8)
  gemm_bt<0><<<32 * 24, 256, 0, stream>>>(xb, wqkv, nullptr, qb, kb, vtb, 3072, 1024);
  // attention
  attn_fwd<<<1024, 256, 0, stream>>>(qb, kb, vtb, ctxb);
  // output projection (+bo)
  gemm_bt<1><<<32 * 8, 256, 0, stream>>>(ctxb, wob, bo, tmp, nullptr, nullptr, 1024, 1024);
  // h = LN(x + attn_out)
  ln_fused<<<4096, 256, 0, stream>>>(x, tmp, g1, b1, hbuf, hbb);
  // ff1 = gelu(h @ w1^T + bf1)
  gemm_bt<2><<<32 * 32, 256, 0, stream>>>(hbb, w1b, bf1, ff1, nullptr, nullptr, 4096, 1024);
  // ff2 = ff1 @ w2^T + bf2
  gemm_bt<1><<<32 * 8, 256, 0, stream>>>(ff1, w2b, bf2, tmp, nullptr, nullptr, 1024, 4096);
  // out = LN(h + ff2)
  ln_fused<<<4096, 256, 0, stream>>>(hbuf, tmp, g2, b2, (float*)d_out, nullptr);
}

// Round 3
// 277.904 us; speedup vs baseline: 1.2844x; 1.1665x over previous
//
#include <hip/hip_runtime.h>
#include <hip/hip_bf16.h>
#include <stdint.h>

typedef __bf16 bf16x8 __attribute__((ext_vector_type(8)));
typedef float  f32x4  __attribute__((ext_vector_type(4)));
typedef unsigned short u16;
typedef u16 u16x8 __attribute__((ext_vector_type(8)));

__device__ __forceinline__ u16 f2b(float f) {
  uint32_t u = __builtin_bit_cast(uint32_t, f);
  u += 0x7fffu + ((u >> 16) & 1u);
  return (u16)(u >> 16);
}

__device__ __forceinline__ f32x4 mfma16(bf16x8 a, bf16x8 b, f32x4 c) {
  return __builtin_amdgcn_mfma_f32_16x16x32_bf16(a, b, c, 0, 0, 0);
}

__device__ __forceinline__ void gload_lds16(const void* g, void* l) {
  __builtin_amdgcn_global_load_lds(
      (const __attribute__((address_space(1))) void*)g,
      (__attribute__((address_space(3))) void*)l, 16, 0, 0);
}

// ---------------- fp32 -> bf16 bulk convert (8 elems/thread) ----------------
__global__ void f2b_conv(const float* __restrict__ in, u16* __restrict__ out, int n8) {
  const int i = blockIdx.x * blockDim.x + threadIdx.x;
  if (i >= n8) return;
  const float4* p = (const float4*)in + (size_t)i * 2;
  float4 a = p[0], b = p[1];
  u16x8 r;
  r[0] = f2b(a.x); r[1] = f2b(a.y); r[2] = f2b(a.z); r[3] = f2b(a.w);
  r[4] = f2b(b.x); r[5] = f2b(b.y); r[6] = f2b(b.z); r[7] = f2b(b.w);
  *((u16x8*)out + i) = r;
}

// ---------------- GEMM: C[M][N] = A[M][K] * W[N][K]^T  (+epilogue) ----------
// MODE 0: QKV scatter (o0=q*(0.125*log2e), o1=k, o2=vt)  [no split]
// MODE 1: fp32 partial out, NO bias (summed in ln_fused)  [split-k via nsplit]
// MODE 2: bf16 out + bias + exact gelu                    [no split]
template<int MODE>
__global__ __launch_bounds__(256, 3) void gemm_bt(
    const u16* __restrict__ A, const u16* __restrict__ W,
    const float* __restrict__ bias,
    void* __restrict__ o0, void* __restrict__ o1, void* __restrict__ o2,
    int Nsz, int Kstride, int Klen, int ntiles)
{
  __shared__ u16 As[2][128 * 32];
  __shared__ u16 Bs[2][128 * 32];
  const int nbn = Nsz >> 7;
  int bid = blockIdx.x;
  bid = (bid & 7) * ((int)gridDim.x >> 3) + (bid >> 3);  // XCD-aware swizzle (grid%8==0)
  const int tile = (MODE == 1) ? (bid % ntiles) : bid;
  const int sid  = (MODE == 1) ? (bid / ntiles) : 0;
  const int koff = sid * Klen;
  const int bm = tile / nbn;
  const int bn = tile % nbn;
  const int tid = threadIdx.x;
  const int w = tid >> 6, l = tid & 63;
  const int lh = l >> 4, ll = l & 15;
  const int wr = w >> 1, wc = w & 1;

  f32x4 acc[4][4] = {};

  const u16* Ag = A + (size_t)(bm * 128) * Kstride + koff;
  const u16* Wg = W + (size_t)(bn * 128) * Kstride + koff;

  const int flat0 = (w * 2) * 64 + l;
  const int flat1 = (w * 2 + 1) * 64 + l;

  // prologue: stage k-step 0 into buf 0
  {
    gload_lds16(Ag + (size_t)(flat0 >> 2) * Kstride + (flat0 & 3) * 8, As[0] + flat0 * 8);
    gload_lds16(Wg + (size_t)(flat0 >> 2) * Kstride + (flat0 & 3) * 8, Bs[0] + flat0 * 8);
    gload_lds16(Ag + (size_t)(flat1 >> 2) * Kstride + (flat1 & 3) * 8, As[0] + flat1 * 8);
    gload_lds16(Wg + (size_t)(flat1 >> 2) * Kstride + (flat1 & 3) * 8, Bs[0] + flat1 * 8);
  }
  __syncthreads();

  const int NS = Klen >> 5;
  int buf = 0;
  for (int s = 0; s < NS; ++s) {
    if (s + 1 < NS) {  // issue next-tile stage first (loads fly under compute)
      const int k0 = (s + 1) * 32;
      gload_lds16(Ag + (size_t)(flat0 >> 2) * Kstride + k0 + (flat0 & 3) * 8, As[buf ^ 1] + flat0 * 8);
      gload_lds16(Wg + (size_t)(flat0 >> 2) * Kstride + k0 + (flat0 & 3) * 8, Bs[buf ^ 1] + flat0 * 8);
      gload_lds16(Ag + (size_t)(flat1 >> 2) * Kstride + k0 + (flat1 & 3) * 8, As[buf ^ 1] + flat1 * 8);
      gload_lds16(Wg + (size_t)(flat1 >> 2) * Kstride + k0 + (flat1 & 3) * 8, Bs[buf ^ 1] + flat1 * 8);
    }
    bf16x8 af[4], bfr[4];
#pragma unroll
    for (int mi = 0; mi < 4; ++mi)
      af[mi] = *(const bf16x8*)(As[buf] + (wr * 64 + mi * 16 + ll) * 32 + lh * 8);
#pragma unroll
    for (int ni = 0; ni < 4; ++ni)
      bfr[ni] = *(const bf16x8*)(Bs[buf] + (wc * 64 + ni * 16 + ll) * 32 + lh * 8);
    __builtin_amdgcn_s_setprio(1);
#pragma unroll
    for (int mi = 0; mi < 4; ++mi)
#pragma unroll
      for (int ni = 0; ni < 4; ++ni)
        acc[mi][ni] = mfma16(af[mi], bfr[ni], acc[mi][ni]);
    __builtin_amdgcn_s_setprio(0);
    __syncthreads();  // drains vmcnt for staged buf^1 + protects dbuf reuse
    buf ^= 1;
  }

#pragma unroll
  for (int mi = 0; mi < 4; ++mi) {
#pragma unroll
    for (int ni = 0; ni < 4; ++ni) {
      const int col = bn * 128 + wc * 64 + ni * 16 + ll;
#pragma unroll
      for (int i = 0; i < 4; ++i) {
        const int row = bm * 128 + wr * 64 + mi * 16 + lh * 4 + i;
        float v = acc[mi][ni][i];
        if (MODE == 1) {
          float* dst = sid ? (float*)o1 : (float*)o0;
          dst[(size_t)row * Nsz + col] = v;
        } else if (MODE == 2) {
          float xx = v + bias[col];
          float gl = 0.5f * xx * (1.0f + erff(xx * 0.70710678118654752f));
          ((u16*)o0)[(size_t)row * Nsz + col] = f2b(gl);
        } else {
          const int which = col >> 10;
          const int e = col & 1023;
          const int hh = e >> 6, dd = e & 63;
          const int bb = row >> 11, nl = row & 2047;
          if (which == 0) {  // q, pre-scaled by (1/sqrt(D)) * log2(e)
            ((u16*)o0)[((size_t)(bb * 16 + hh) * 2048 + nl) * 64 + dd] = f2b(v * 0.18033688f);
          } else if (which == 1) {
            ((u16*)o1)[((size_t)(bb * 16 + hh) * 2048 + nl) * 64 + dd] = f2b(v);
          } else {
            ((u16*)o2)[((size_t)(bb * 16 + hh) * 64 + dd) * 2048 + nl] = f2b(v);
          }
        }
      }
    }
  }
}

// ---------------- flash attention (non-causal), swapped QK^T, log2 domain ---
// Q,K: bf16 [32][2048][64] (Q pre-scaled); Vt: bf16 [32][64][2048]; ctx: bf16 [4096][1024]
__global__ __launch_bounds__(256, 4) void attn_fwd(
    const u16* __restrict__ Q, const u16* __restrict__ K,
    const u16* __restrict__ Vt, u16* __restrict__ ctx)
{
  __shared__ u16 Ks[2][64 * 64];
  __shared__ u16 Vs[2][64 * 64];
  __shared__ u16 Ps[4][16 * 64];

  const int bh = blockIdx.x & 31;
  const int qt = blockIdx.x >> 5;
  const int tid = threadIdx.x;
  const int w = tid >> 6, l = tid & 63;
  const int lh = l >> 4, ll = l & 15;
  const int q0 = qt * 64 + w * 16;

  bf16x8 qf[2];
  {
    const u16* Qg = Q + ((size_t)bh * 2048 + q0 + ll) * 64;
#pragma unroll
    for (int kk = 0; kk < 2; ++kk)
      qf[kk] = *(const bf16x8*)(Qg + kk * 32 + lh * 8);
  }

  bf16x8 ones;
  {
    const u16 o = 0x3F80;  // bf16 1.0
#pragma unroll
    for (int i = 0; i < 8; ++i) ones[i] = __builtin_bit_cast(__bf16, o);
  }

  f32x4 cacc[4] = {};
  f32x4 lacc = {};     // per-query row-sum of P (C-layout), via mfma(P, ones)
  float m_l = -1e30f;  // running max (log2 domain) for query ll
  u16* ps = Ps[w];

  const int f0 = tid, f1 = 256 + tid;
  const int r0 = f0 >> 3, s0 = f0 & 7, g0 = (s0 ^ (r0 & 7)) * 8;
  const int r1 = f1 >> 3, s1 = f1 & 7, g1 = (s1 ^ (r1 & 7)) * 8;

  // prologue: stage kt=0 into buf 0 (swizzled source, linear LDS dest)
  {
    gload_lds16(K + ((size_t)bh * 2048 + r0) * 64 + g0, Ks[0] + f0 * 8);
    gload_lds16(Vt + ((size_t)bh * 64 + r0) * 2048 + g0, Vs[0] + f0 * 8);
    gload_lds16(K + ((size_t)bh * 2048 + r1) * 64 + g1, Ks[0] + f1 * 8);
    gload_lds16(Vt + ((size_t)bh * 64 + r1) * 2048 + g1, Vs[0] + f1 * 8);
  }
  __syncthreads();

  for (int kt = 0; kt < 32; ++kt) {
    const int b = kt & 1;
    if (kt < 31) {  // stage kt+1 early; drains only at end-of-tile barrier
      const int kn = (kt + 1) * 64;
      gload_lds16(K + ((size_t)bh * 2048 + kn + r0) * 64 + g0, Ks[b ^ 1] + f0 * 8);
      gload_lds16(Vt + ((size_t)bh * 64 + r0) * 2048 + kn + g0, Vs[b ^ 1] + f0 * 8);
      gload_lds16(K + ((size_t)bh * 2048 + kn + r1) * 64 + g1, Ks[b ^ 1] + f1 * 8);
      gload_lds16(Vt + ((size_t)bh * 64 + r1) * 2048 + kn + g1, Vs[b ^ 1] + f1 * 8);
    }

    // S^T = K Q^T (log2 domain): lane holds S[key=jb*16+lh*4+i][q=ll]
    f32x4 st[4];
    __builtin_amdgcn_s_setprio(1);
#pragma unroll
    for (int jb = 0; jb < 4; ++jb) {
      f32x4 a = {};
#pragma unroll
      for (int kk = 0; kk < 2; ++kk) {
        const int r = jb * 16 + ll;
        bf16x8 kf = *(const bf16x8*)(Ks[b] + r * 64 + (((kk * 4 + lh) ^ (r & 7)) * 8));
        a = mfma16(kf, qf[kk], a);  // swapped: A=K, B=Q
      }
      st[jb] = a;
    }
    __builtin_amdgcn_s_setprio(0);

    // per-lane max over 16 regs + cross-lh reduce
    float mx = fmaxf(fmaxf(fmaxf(st[0][0], st[0][1]), fmaxf(st[0][2], st[0][3])),
                     fmaxf(fmaxf(st[1][0], st[1][1]), fmaxf(st[1][2], st[1][3])));
    mx = fmaxf(mx, fmaxf(fmaxf(fmaxf(st[2][0], st[2][1]), fmaxf(st[2][2], st[2][3])),
                         fmaxf(fmaxf(st[3][0], st[3][1]), fmaxf(st[3][2], st[3][3]))));
    mx = fmaxf(mx, __shfl_xor(mx, 16));
    mx = fmaxf(mx, __shfl_xor(mx, 32));

    // defer-max (T13): rescale only when max grew past threshold (log2 units)
    if (!__all(mx - m_l <= 8.0f)) {
      const float mn = fmaxf(m_l, mx);
      const float al = __builtin_amdgcn_exp2f(m_l - mn);
      m_l = mn;
      float alq[4];
#pragma unroll
      for (int i = 0; i < 4; ++i) alq[i] = __shfl(al, lh * 4 + i);
#pragma unroll
      for (int db = 0; db < 4; ++db)
#pragma unroll
        for (int i = 0; i < 4; ++i) cacc[db][i] *= alq[i];
#pragma unroll
      for (int i = 0; i < 4; ++i) lacc[i] *= alq[i];
    }

    // P = exp2(S - m), pack via v_cvt_pk_bf16_f32, store to wave-private LDS
#pragma unroll
    for (int jb = 0; jb < 4; ++jb) {
      const float p0 = __builtin_amdgcn_exp2f(st[jb][0] - m_l);
      const float p1 = __builtin_amdgcn_exp2f(st[jb][1] - m_l);
      const float p2 = __builtin_amdgcn_exp2f(st[jb][2] - m_l);
      const float p3 = __builtin_amdgcn_exp2f(st[jb][3] - m_l);
      uint2 pk;
      asm("v_cvt_pk_bf16_f32 %0, %1, %2" : "=v"(pk.x) : "v"(p0), "v"(p1));
      asm("v_cvt_pk_bf16_f32 %0, %1, %2" : "=v"(pk.y) : "v"(p2), "v"(p3));
      *(uint2*)(ps + ll * 64 + (((jb * 2 + (lh >> 1)) ^ (ll & 7)) * 8) + (lh & 1) * 4) = pk;
    }

    asm volatile("s_waitcnt lgkmcnt(0)" ::: "memory");
    __builtin_amdgcn_sched_barrier(0);

    // ctx += P * V ; row-sums l += P @ 1 (same A-fragment, free B)
    __builtin_amdgcn_s_setprio(1);
#pragma unroll
    for (int kk = 0; kk < 2; ++kk) {
      bf16x8 pf = *(const bf16x8*)(ps + ll * 64 + (((kk * 4 + lh) ^ (ll & 7)) * 8));
      lacc = mfma16(pf, ones, lacc);
#pragma unroll
      for (int db = 0; db < 4; ++db) {
        const int vr = db * 16 + ll;
        bf16x8 vf = *(const bf16x8*)(Vs[b] + vr * 64 + (((kk * 4 + lh) ^ (vr & 7)) * 8));
        cacc[db] = mfma16(pf, vf, cacc[db]);
      }
    }
    __builtin_amdgcn_s_setprio(0);
    __syncthreads();  // drains staged loads for kt+1, protects dbuf
  }

  const int bb = bh >> 4, hh = bh & 15;
#pragma unroll
  for (int db = 0; db < 4; ++db)
#pragma unroll
    for (int i = 0; i < 4; ++i) {
      const float v = cacc[db][i] / lacc[i];
      const size_t orow = (size_t)bb * 2048 + q0 + lh * 4 + i;
      const size_t ocol = (size_t)hh * 64 + db * 16 + ll;
      ctx[orow * 1024 + ocol] = f2b(v);
    }
}

// -------- fused residual + partial-sum + bias + LayerNorm (row = 1024 fp32) -
__global__ __launch_bounds__(256) void ln_fused(
    const float* __restrict__ a, const float* __restrict__ b0,
    const float* __restrict__ b1, const float* __restrict__ bias,
    const float* __restrict__ g, const float* __restrict__ be,
    float* __restrict__ ho, u16* __restrict__ hb)
{
  const int row = blockIdx.x;
  const int t = threadIdx.x;
  const size_t base = (size_t)row * 1024 + t * 4;
  float4 xa = *(const float4*)(a + base);
  float4 xb = *(const float4*)(b0 + base);
  float v0 = xa.x + xb.x, v1 = xa.y + xb.y, v2 = xa.z + xb.z, v3 = xa.w + xb.w;
  if (b1) {
    float4 xc = *(const float4*)(b1 + base);
    v0 += xc.x; v1 += xc.y; v2 += xc.z; v3 += xc.w;
  }
  if (bias) {
    float4 xd = *(const float4*)(bias + t * 4);
    v0 += xd.x; v1 += xd.y; v2 += xd.z; v3 += xd.w;
  }
  float s = v0 + v1 + v2 + v3;
  float ss = v0 * v0 + v1 * v1 + v2 * v2 + v3 * v3;
#pragma unroll
  for (int d = 1; d < 64; d <<= 1) {
    s += __shfl_xor(s, d);
    ss += __shfl_xor(ss, d);
  }
  __shared__ float red[8];
  const int w = t >> 6, lid = t & 63;
  if (lid == 0) { red[w] = s; red[4 + w] = ss; }
  __syncthreads();
  s = red[0] + red[1] + red[2] + red[3];
  ss = red[4] + red[5] + red[6] + red[7];
  const float mean = s * (1.0f / 1024.0f);
  const float var = ss * (1.0f / 1024.0f) - mean * mean;
  const float rstd = rsqrtf(var + 1e-5f);
  const float vv[4] = {v0, v1, v2, v3};
#pragma unroll
  for (int i = 0; i < 4; ++i) {
    const int col = t * 4 + i;
    const float hv = (vv[i] - mean) * rstd * g[col] + be[col];
    if (ho) ho[base + i] = hv;
    if (hb) hb[base + i] = f2b(hv);
  }
}

// ---------------------------------------------------------------------------
extern "C" void kernel_launch(void* const* d_in, const int* in_sizes, int n_in,
                              void* d_out, int out_size, void* d_ws, size_t ws_size,
                              hipStream_t stream) {
  const float* x   = (const float*)d_in[0];
  const float* wq  = (const float*)d_in[1];
  const float* wk  = (const float*)d_in[2];
  const float* wv  = (const float*)d_in[3];
  const float* wo  = (const float*)d_in[4];
  const float* bo  = (const float*)d_in[5];
  const float* g1  = (const float*)d_in[6];
  const float* b1  = (const float*)d_in[7];
  const float* w1  = (const float*)d_in[8];
  const float* bf1 = (const float*)d_in[9];
  const float* w2  = (const float*)d_in[10];
  const float* bf2 = (const float*)d_in[11];
  const float* g2  = (const float*)d_in[12];
  const float* b2  = (const float*)d_in[13];

  char* ws = (char*)d_ws;
  const size_t MB = 1u << 20;
  u16* xb    = (u16*)(ws + 0);        //  8 MB  x bf16 [4096][1024]
  u16* wqkv  = (u16*)(ws + 8 * MB);   //  6 MB  wq|wk|wv bf16 [3072][1024]
  u16* wob   = (u16*)(ws + 14 * MB);  //  2 MB
  u16* w1b   = (u16*)(ws + 16 * MB);  //  8 MB
  u16* w2b   = (u16*)(ws + 24 * MB);  //  8 MB
  u16* qb    = (u16*)(ws + 32 * MB);  //  8 MB  [32][2048][64]
  u16* kb    = (u16*)(ws + 40 * MB);  //  8 MB
  u16* vtb   = (u16*)(ws + 48 * MB);  //  8 MB  [32][64][2048]
  u16* ctxb  = (u16*)(ws + 56 * MB);  //  8 MB  [4096][1024]
  float* p0buf = (float*)(ws + 64 * MB);  // 16 MB  split-k partial 0 (WO, then FF2)
  float* hbuf  = (float*)(ws + 80 * MB);  // 16 MB  h fp32
  u16* hbb   = (u16*)(ws + 96 * MB);  //  8 MB  h bf16
  float* wo_p1 = (float*)(ws + 32 * MB);  // 16 MB  WO partial 1 (q/k dead)
  float* f2_p1 = (float*)(ws + 0);        // 16 MB  FF2 partial 1 (xb/wqkv dead)
  u16* ff1   = (u16*)(ws + 32 * MB);  // 32 MB  FF1 out (q/k/vt/ctx dead)

  // fp32 -> bf16
  f2b_conv<<<2048, 256, 0, stream>>>(x, xb, 524288);
  f2b_conv<<<512, 256, 0, stream>>>(wq, wqkv, 131072);
  f2b_conv<<<512, 256, 0, stream>>>(wk, wqkv + 1048576, 131072);
  f2b_conv<<<512, 256, 0, stream>>>(wv, wqkv + 2097152, 131072);
  f2b_conv<<<512, 256, 0, stream>>>(wo, wob, 131072);
  f2b_conv<<<2048, 256, 0, stream>>>(w1, w1b, 524288);
  f2b_conv<<<2048, 256, 0, stream>>>(w2, w2b, 524288);

  // fused QKV projection (q pre-scaled by 0.125*log2e)
  gemm_bt<0><<<768, 256, 0, stream>>>(xb, wqkv, nullptr, qb, kb, vtb, 3072, 1024, 1024, 768);
  // attention
  attn_fwd<<<1024, 256, 0, stream>>>(qb, kb, vtb, ctxb);
  // output projection, split-k=2 (bias bo folded into LN1)
  gemm_bt<1><<<512, 256, 0, stream>>>(ctxb, wob, nullptr, p0buf, wo_p1, nullptr, 1024, 1024, 512, 256);
  // h = LN(x + wo_p0 + wo_p1 + bo)
  ln_fused<<<4096, 256, 0, stream>>>(x, p0buf, wo_p1, bo, g1, b1, hbuf, hbb);
  // ff1 = gelu(h @ w1^T + bf1)
  gemm_bt<2><<<1024, 256, 0, stream>>>(hbb, w1b, bf1, ff1, nullptr, nullptr, 4096, 1024, 1024, 1024);
  // ff2 = ff1 @ w2^T, split-k=2 (bias bf2 folded into LN2)
  gemm_bt<1><<<512, 256, 0, stream>>>(ff1, w2b, nullptr, p0buf, f2_p1, nullptr, 1024, 4096, 2048, 256);
  // out = LN(h + f2_p0 + f2_p1 + bf2)
  ln_fused<<<4096, 256, 0, stream>>>(hbuf, p0buf, f2_p1, bf2, g2, b2, (float*)d_out, nullptr);
}